// Round 6
// baseline (275.885 us; speedup 1.0000x reference)
//
#include <hip/hip_runtime.h>
#include <math.h>

#define TOK 1568      // B*N = 8*196
#define MPAD 1664     // 13 * 128
#define DIM 768
#define HN 12
#define SEQ 196
#define YD 64
#define MXI 3072
#define BETA_F 0.125f
#define INV_BETA 8.0f
#define LN_EPS_F 1e-5f

// P/PT padded geometry: rows 208 (13*16), cols 224 (7*32)
#define PROWS 208
#define PCOLS 224
#define PAREA (PROWS * PCOLS)

// energy partials (doubles):
// attn ver*96+bh, ver 0..4 -> [0,480)   (bank A / half0)
// hop base [480,792) ; hop trial t*312 -> [792,2040)
// trial attn bank B (half1): 2040 + t*96 + bh -> [2040,2424)
// base attn bank B (half1): 2424 + bh -> [2424,2520)
#define EP_HOPB 480
#define EP_HOPT 792
#define EP_A2T 2040
#define EP_A2B 2424
#define EP_TOTAL 2520

#define NPE ((size_t)MPAD * DIM)

// attn-core LDS layout (bytes): Ks[208*72] | Qs[208*72] | er[8]
#define OFF_QS 29952
#define OFF_ER 59904
#define SM_ATTN 59968

typedef __bf16 v8bf __attribute__((ext_vector_type(8)));
typedef __bf16 v4bf __attribute__((ext_vector_type(4)));
typedef float  v4f  __attribute__((ext_vector_type(4)));
typedef int    v4i  __attribute__((ext_vector_type(4)));
typedef int    v8i  __attribute__((ext_vector_type(8)));

__device__ __forceinline__ v8bf zero8() {
  v8bf v = { (__bf16)0.f, (__bf16)0.f, (__bf16)0.f, (__bf16)0.f,
             (__bf16)0.f, (__bf16)0.f, (__bf16)0.f, (__bf16)0.f };
  return v;
}

// ------------------------------------------------------------------
// Stage one 128x32 bf16 tile into LDS (global_load_lds width=16).
// ------------------------------------------------------------------
__device__ __forceinline__ void stage_tile(
    const __bf16* __restrict__ G, int ldK, int r0, int k0,
    __bf16* S, int tid, int w)
{
#pragma unroll
  for (int r = 0; r < 2; r++) {
    int ch = (r << 8) + tid;
    int row = ch >> 2;
    int col = (ch & 3) ^ ((row >> 1) & 3);
    __builtin_amdgcn_global_load_lds(
        (__attribute__((address_space(1))) uint32_t*)(G + (size_t)(r0 + row) * ldK + k0 + (col << 3)),
        (__attribute__((address_space(3))) uint32_t*)(S + (r << 11) + (w << 9)),
        16, 0, 0);
  }
}

// ------------------------------------------------------------------
// bf16 MFMA GEMM core: acc += A[m0:+128, kbase:+nk*32] @ B[n0:+128]^T
// smem: As 2x4096 bf16 | Bs 2x4096 bf16 (32768 B)
// ------------------------------------------------------------------
__device__ __forceinline__ void gemm_core_bf16(
    char* smem, const __bf16* __restrict__ A, int ldA,
    const __bf16* __restrict__ B, int ldB,
    int m0, int n0, int kbase, int nk, v4f acc[4][4], int tid)
{
  __bf16* As = (__bf16*)smem;
  __bf16* Bs = (__bf16*)smem + 8192;
  int lane = tid & 63, w = tid >> 6;
  int wm = (w & 1) << 6, wn = (w >> 1) << 6;
  stage_tile(A, ldA, m0, kbase, As, tid, w);
  stage_tile(B, ldB, n0, kbase, Bs, tid, w);
  for (int kt = 0; kt < nk; kt++) {
    __syncthreads();
    int nxt = kt + 1;
    if (nxt < nk) {
      stage_tile(A, ldA, m0, kbase + (nxt << 5), As + ((nxt & 1) << 12), tid, w);
      stage_tile(B, ldB, n0, kbase + (nxt << 5), Bs + ((nxt & 1) << 12), tid, w);
    }
    const __bf16* Ac = As + ((kt & 1) << 12);
    const __bf16* Bc = Bs + ((kt & 1) << 12);
    int mrow = lane & 15, q = lane >> 4;
    v8bf af[4], bfr[4];
#pragma unroll
    for (int i = 0; i < 4; i++) {
      int rA = wm + (i << 4) + mrow;
      int rB = wn + (i << 4) + mrow;
      af[i]  = *(const v8bf*)(Ac + rA * 32 + ((q ^ ((rA >> 1) & 3)) << 3));
      bfr[i] = *(const v8bf*)(Bc + rB * 32 + ((q ^ ((rB >> 1) & 3)) << 3));
    }
#pragma unroll
    for (int i = 0; i < 4; i++)
#pragma unroll
      for (int j = 0; j < 4; j++)
        acc[i][j] = __builtin_amdgcn_mfma_f32_16x16x32_bf16(af[i], bfr[j], acc[i][j], 0, 0, 0);
  }
}

__device__ __forceinline__ void acc_zero(v4f acc[4][4]) {
  v4f z = {0.f, 0.f, 0.f, 0.f};
#pragma unroll
  for (int i = 0; i < 4; i++)
#pragma unroll
    for (int j = 0; j < 4; j++) acc[i][j] = z;
}

__device__ __forceinline__ void epi_store_f32(
    v4f acc[4][4], float* C, int m0, int n0, int tid)
{
  int lane = tid & 63, w = tid >> 6;
  int wm = (w & 1) << 6, wn = (w >> 1) << 6;
  int quad = lane >> 4, ncol = lane & 15;
#pragma unroll
  for (int i = 0; i < 4; i++)
#pragma unroll
    for (int j = 0; j < 4; j++) {
      int row = m0 + wm + (i << 4) + (quad << 2);
      int col = n0 + wn + (j << 4) + ncol;
#pragma unroll
      for (int r = 0; r < 4; r++)
        C[(size_t)(row + r) * DIM + col] = acc[i][j][r];
    }
}

// bf16 store epilogue with arbitrary ldC
__device__ __forceinline__ void epi_store_bf16_ld(
    v4f acc[4][4], __bf16* C, int ldC, int m0, int n0, int tid)
{
  int lane = tid & 63, w = tid >> 6;
  int wm = (w & 1) << 6, wn = (w >> 1) << 6;
  int quad = lane >> 4, ncol = lane & 15;
#pragma unroll
  for (int i = 0; i < 4; i++)
#pragma unroll
    for (int j = 0; j < 4; j++) {
      int row = m0 + wm + (i << 4) + (quad << 2);
      int col = n0 + wn + (j << 4) + ncol;
#pragma unroll
      for (int r = 0; r < 4; r++)
        C[(size_t)(row + r) * ldC + col] = (__bf16)acc[i][j][r];
    }
}

__device__ __forceinline__ void epi_relu_energy(
    v4f acc[4][4], __bf16* C, int N, int m0, int n0, int tid,
    double* ered, double* ep_slot)
{
  int lane = tid & 63, w = tid >> 6;
  int wm = (w & 1) << 6, wn = (w >> 1) << 6;
  int quad = lane >> 4, ncol = lane & 15;
  float e = 0.f;
#pragma unroll
  for (int i = 0; i < 4; i++)
#pragma unroll
    for (int j = 0; j < 4; j++) {
      int row = m0 + wm + (i << 4) + (quad << 2);
      int col = n0 + wn + (j << 4) + ncol;
#pragma unroll
      for (int r = 0; r < 4; r++) {
        float v = acc[i][j][r];
        v = v > 0.f ? v : 0.f;
        e += v * v;
        C[(size_t)(row + r) * N + col] = (__bf16)v;
      }
    }
  for (int o = 32; o; o >>= 1) e += __shfl_xor(e, o, 64);
  if (lane == 0) ered[w] = (double)e;
  __syncthreads();
  if (tid == 0)
    *ep_slot = -0.5 * ((ered[0] + ered[1]) + (ered[2] + ered[3]));
}

// ------------------------------------------------------------------
// MX fp8 (e4m3, unit scales) GEMM, energy only (trial hopfield).
// SINGLE-buffered BK=128 staging: As 16384 | Bs 16384 | ered 32
// (32800 B -> 4 blocks/CU; inter-block TLP covers stage/compute serial).
// Same MFMAs / accumulation order as before — bit-identical results.
// ------------------------------------------------------------------
__device__ __forceinline__ void stage_mx(
    const unsigned char* __restrict__ A0, const unsigned char* __restrict__ B0,
    unsigned char* As, unsigned char* Bs, int m0, int n0, int k0, int tid)
{
#pragma unroll
  for (int rr = 0; rr < 4; rr++) {
    int ch = (rr << 8) + tid;          // chunk 0..1023
    int row = ch >> 3;                 // 0..127
    int gc = ((ch & 7) ^ (row & 7)) << 4;
    int dst = (rr << 12) + ((tid >> 6) << 10);   // + lane*16 by HW
    __builtin_amdgcn_global_load_lds(
        (__attribute__((address_space(1))) uint32_t*)(A0 + (size_t)(m0 + row) * DIM + k0 + gc),
        (__attribute__((address_space(3))) uint32_t*)(As + dst), 16, 0, 0);
    __builtin_amdgcn_global_load_lds(
        (__attribute__((address_space(1))) uint32_t*)(B0 + (size_t)(n0 + row) * DIM + k0 + gc),
        (__attribute__((address_space(3))) uint32_t*)(Bs + dst), 16, 0, 0);
  }
}

__device__ __forceinline__ void dev_gemm_mx8(
    char* smem, const unsigned char* __restrict__ A0,
    const unsigned char* __restrict__ B0, double* __restrict__ ep,
    int my, int nx, int tid)
{
  unsigned char* As = (unsigned char*)smem;           // 16384
  unsigned char* Bs = (unsigned char*)smem + 16384;   // 16384
  double* ered = (double*)(smem + 32768);
  int lane = tid & 63, w = tid >> 6;
  int wm = (w & 1) << 6, wn = (w >> 1) << 6;
  int m0 = my * 128, n0 = nx * 128;

  v4f acc[4][4];
  acc_zero(acc);

  const int nk = 6;   // 768 / 128
  for (int kt = 0; kt < nk; kt++) {
    stage_mx(A0, B0, As, Bs, m0, n0, kt << 7, tid);
    __syncthreads();
    int mrow = lane & 15, qs = lane >> 4;
    v8i af[4], bfr[4];
#pragma unroll
    for (int i = 0; i < 4; i++) {
      int rA = wm + (i << 4) + mrow;
      int rB = wn + (i << 4) + mrow;
      int sa = rA & 7, sb = rB & 7;
      v4i alo = *(const v4i*)(As + rA * 128 + ((((qs << 1)) ^ sa) << 4));
      v4i ahi = *(const v4i*)(As + rA * 128 + ((((qs << 1) | 1) ^ sa) << 4));
      v4i blo = *(const v4i*)(Bs + rB * 128 + ((((qs << 1)) ^ sb) << 4));
      v4i bhi = *(const v4i*)(Bs + rB * 128 + ((((qs << 1) | 1) ^ sb) << 4));
      af[i]  = __builtin_shufflevector(alo, ahi, 0, 1, 2, 3, 4, 5, 6, 7);
      bfr[i] = __builtin_shufflevector(blo, bhi, 0, 1, 2, 3, 4, 5, 6, 7);
    }
#pragma unroll
    for (int i = 0; i < 4; i++)
#pragma unroll
      for (int j = 0; j < 4; j++)
        acc[i][j] = __builtin_amdgcn_mfma_scale_f32_16x16x128_f8f6f4(
            af[i], bfr[j], acc[i][j], 0, 0, 0, 127, 0, 127);
    __syncthreads();
  }

  float e = 0.f;
#pragma unroll
  for (int i = 0; i < 4; i++)
#pragma unroll
    for (int j = 0; j < 4; j++)
#pragma unroll
      for (int r = 0; r < 4; r++) {
        float v = acc[i][j][r];
        v = v > 0.f ? v : 0.f;
        e += v * v;
      }
  for (int o = 32; o; o >>= 1) e += __shfl_xor(e, o, 64);
  if (lane == 0) ered[w] = (double)e;
  __syncthreads();
  if (tid == 0) {
    double tot = (ered[0] + ered[1]) + (ered[2] + ered[3]);
    int tt = my / 13, ry = my - tt * 13;
    ep[EP_HOPT + tt * 312 + ry * 24 + nx] = (-0.5 / 256.0) * tot;
  }
}

// ------------------------------------------------------------------
// Attention core on prefilled Ks/Qs (stride 72). NW = waves per block.
// Processes mt in [mt_begin, mt_end) strided by NW. SP=1: store P+energy.
// ------------------------------------------------------------------
template <int SP, int NW>
__device__ __forceinline__ void dev_attn_core(
    char* smem, __bf16* __restrict__ P, size_t Pbase,
    double* __restrict__ ep_slot, int mt_begin, int mt_end, int tid)
{
  __bf16* Ks = (__bf16*)smem;
  __bf16* Qs = (__bf16*)(smem + OFF_QS);
  double* er = (double*)(smem + OFF_ER);
  int lane = tid & 63, w = tid >> 6;
  int mrow = lane & 15, quad = lane >> 4, ncol = mrow;
  int ksel = quad * 8;
  v4f zero = {0.f, 0.f, 0.f, 0.f};
  double eacc = 0.0;

  for (int mt = mt_begin + w; mt < mt_end; mt += NW) {
    int m0 = mt * 16;
    v8bf af0 = *(const v8bf*)(Qs + (m0 + mrow) * 72 + ksel);
    v8bf af1 = *(const v8bf*)(Qs + (m0 + mrow) * 72 + 32 + ksel);
    v4f acc[13];
#pragma unroll
    for (int j = 0; j < 13; j++) {
      v8bf bf0 = *(const v8bf*)(Ks + (j * 16 + mrow) * 72 + ksel);
      v8bf bf1 = *(const v8bf*)(Ks + (j * 16 + mrow) * 72 + 32 + ksel);
      v4f t = __builtin_amdgcn_mfma_f32_16x16x32_bf16(af0, bf0, zero, 0, 0, 0);
      acc[j] = __builtin_amdgcn_mfma_f32_16x16x32_bf16(af1, bf1, t, 0, 0, 0);
    }
    float mx[4] = {-1e30f, -1e30f, -1e30f, -1e30f};
#pragma unroll
    for (int j = 0; j < 13; j++) {
      bool colv = (j < 12) || (ncol < 4);
#pragma unroll
      for (int r = 0; r < 4; r++) {
        float sv = colv ? BETA_F * acc[j][r] : -1e30f;
        acc[j][r] = sv;
        mx[r] = fmaxf(mx[r], sv);
      }
    }
#pragma unroll
    for (int o = 1; o < 16; o <<= 1)
#pragma unroll
      for (int r = 0; r < 4; r++) mx[r] = fmaxf(mx[r], __shfl_xor(mx[r], o, 64));
    float zr[4] = {0.f, 0.f, 0.f, 0.f};
#pragma unroll
    for (int j = 0; j < 13; j++)
#pragma unroll
      for (int r = 0; r < 4; r++) {
        float t = (acc[j][r] > -1e29f) ? expf(acc[j][r] - mx[r]) : 0.f;
        acc[j][r] = t;
        zr[r] += t;
      }
#pragma unroll
    for (int o = 1; o < 16; o <<= 1)
#pragma unroll
      for (int r = 0; r < 4; r++) zr[r] += __shfl_xor(zr[r], o, 64);
    if (ncol == 0) {
#pragma unroll
      for (int r = 0; r < 4; r++) {
        int q = m0 + quad * 4 + r;
        if (q < SEQ) eacc += (double)(mx[r] + logf(zr[r]));
      }
    }
    if (SP) {
      float inv[4];
#pragma unroll
      for (int r = 0; r < 4; r++) inv[r] = 1.f / zr[r];
      size_t Pb = Pbase + (size_t)(m0 + quad * 4) * PCOLS;
#pragma unroll
      for (int j = 0; j < 13; j++)
#pragma unroll
        for (int r = 0; r < 4; r++) {
          int q = m0 + quad * 4 + r;
          float pv = (q < SEQ) ? acc[j][r] * inv[r] : 0.f;
          P[Pb + (size_t)r * PCOLS + j * 16 + ncol] = (__bf16)pv;
        }
#pragma unroll
      for (int r = 0; r < 4; r++)
        P[Pb + (size_t)r * PCOLS + 208 + ncol] = (__bf16)0.f;
    }
  }
  for (int o = 32; o; o >>= 1) eacc += __shfl_xor(eacc, o, 64);
  if (lane == 0) er[w] = eacc;
  __syncthreads();
  if (tid == 0) {
    double s = 0.0;
#pragma unroll
    for (int i = 0; i < NW; i++) s += er[i];
    *ep_slot = -(double)INV_BETA * s;
  }
}

// stage K/Q [208x64] slabs from KQ buffer (ld 1536) into Ks/Qs (stride 72)
template <int NT>
__device__ __forceinline__ void dev_stage_kq(
    char* smem, const __bf16* __restrict__ Ksrc, int tid)
{
  const __bf16* Qsrc = Ksrc + 768;
  __bf16* Ks = (__bf16*)smem;
  __bf16* Qs = (__bf16*)(smem + OFF_QS);
  for (int i = tid; i < PROWS * 8; i += NT) {
    int row = i >> 3, c = (i & 7) << 3;
    v8bf kv = zero8(), qv = zero8();
    if (row < SEQ) {
      kv = *(const v8bf*)(Ksrc + (size_t)row * 1536 + c);
      qv = *(const v8bf*)(Qsrc + (size_t)row * 1536 + c);
    }
    *(v8bf*)(Ks + row * 72 + c) = kv;
    *(v8bf*)(Qs + row * 72 + c) = qv;
  }
  __syncthreads();
}

// ------------------------------------------------------------------
// MFMA attention backward one side. smem: BT 29696 B.
// z=0: dQ = -(P@K); z=1: dK = -(PT@Q).  K/Q read from KQb (ld 1536).
// ------------------------------------------------------------------
__device__ __forceinline__ void dev_attn_bwd(
    char* smem, const __bf16* __restrict__ KQb,
    const __bf16* __restrict__ Pg, const __bf16* __restrict__ PTg,
    __bf16* __restrict__ dQg, __bf16* __restrict__ dKg,
    int bh, int z, int tid)
{
  __bf16* BT = (__bf16*)smem;   // 64 x 232
  int b = bh / HN, h = bh - b * HN;
  const __bf16* Bsrc = KQb + (size_t)(b * SEQ) * 1536 + (z ? 768 : 0) + h * YD;
  const __bf16* Asrc = (z ? PTg : Pg) + (size_t)bh * PAREA;
  __bf16* Dst = (z ? dKg : dQg) + (size_t)(b * SEQ) * DIM + h * YD;
  for (int i = tid; i < 64 * 232 / 8; i += 256) ((v8bf*)BT)[i] = zero8();
  __syncthreads();
  for (int i = tid; i < SEQ * 8; i += 256) {
    int k = i >> 3, c = i & 7;
    v8bf v = *(const v8bf*)(Bsrc + (size_t)k * 1536 + c * 8);
#pragma unroll
    for (int e = 0; e < 8; e++) BT[(c * 8 + e) * 232 + k] = v[e];
  }
  __syncthreads();

  int lane = tid & 63, w = tid >> 6;
  int mrow = lane & 15, quad = lane >> 4, ncol = mrow;
  int ksel = quad * 8;
  for (int mt = w; mt < 13; mt += 4) {
    int m0 = mt * 16;
    v4f acc[4];
    v4f zero = {0.f, 0.f, 0.f, 0.f};
#pragma unroll
    for (int n = 0; n < 4; n++) acc[n] = zero;
    v8bf afc = *(const v8bf*)(Asrc + (size_t)(m0 + mrow) * PCOLS + ksel);
#pragma unroll
    for (int s = 0; s < 7; s++) {
      v8bf afn = (s < 6)
          ? *(const v8bf*)(Asrc + (size_t)(m0 + mrow) * PCOLS + (s + 1) * 32 + ksel)
          : zero8();
#pragma unroll
      for (int n = 0; n < 4; n++) {
        v8bf bf = *(const v8bf*)(BT + (n * 16 + mrow) * 232 + s * 32 + ksel);
        acc[n] = __builtin_amdgcn_mfma_f32_16x16x32_bf16(afc, bf, acc[n], 0, 0, 0);
      }
      afc = afn;
    }
    int row = m0 + quad * 4;
#pragma unroll
    for (int n = 0; n < 4; n++)
#pragma unroll
      for (int r = 0; r < 4; r++)
        if (row + r < SEQ)
          Dst[(size_t)(row + r) * DIM + n * 16 + ncol] = (__bf16)(-acc[n][r]);
  }
}

// ==================================================================
// Dispatch 1: prep = ln_fwd(1568) | cvtall(3456) | cvtT(3456) | init(288)
// ==================================================================
__global__ __launch_bounds__(256) void prep_k(
    const float* __restrict__ x, const float* __restrict__ gamma,
    const float* __restrict__ delta, const float* __restrict__ wk,
    const float* __restrict__ wq, const float* __restrict__ xi,
    __bf16* __restrict__ g, float* __restrict__ xhat, float* __restrict__ rstd,
    __bf16* __restrict__ wk_bf, __bf16* __restrict__ wq_bf,
    __bf16* __restrict__ xi_bf, int* __restrict__ xi8,
    __bf16* __restrict__ wkT, __bf16* __restrict__ wqT, __bf16* __restrict__ xiT,
    __bf16* __restrict__ gt, unsigned char* __restrict__ g8,
    __bf16* __restrict__ dq, __bf16* __restrict__ dk)
{
  __shared__ float s[4];
  __shared__ float tt[32][33];
  int blk = blockIdx.x, tid = threadIdx.x;
  if (blk < 1568) {
    int tok = blk;
    const float* xp = x + (size_t)tok * DIM;
    float v0 = xp[tid], v1 = xp[tid + 256], v2 = xp[tid + 512];
    float sum = v0 + v1 + v2;
    for (int o = 32; o; o >>= 1) sum += __shfl_xor(sum, o, 64);
    if ((tid & 63) == 0) s[tid >> 6] = sum;
    __syncthreads();
    float mu = (s[0] + s[1] + s[2] + s[3]) * (1.0f / DIM);
    __syncthreads();
    float d0 = v0 - mu, d1 = v1 - mu, d2 = v2 - mu;
    float sq = d0 * d0 + d1 * d1 + d2 * d2;
    for (int o = 32; o; o >>= 1) sq += __shfl_xor(sq, o, 64);
    if ((tid & 63) == 0) s[tid >> 6] = sq;
    __syncthreads();
    float var = (s[0] + s[1] + s[2] + s[3]) * (1.0f / DIM);
    float r = rsqrtf(var + LN_EPS_F);
    float xh0 = d0 * r, xh1 = d1 * r, xh2 = d2 * r;
    size_t base = (size_t)tok * DIM;
    g[base + tid]       = (__bf16)(gamma[tid] * xh0 + delta[tid]);
    g[base + tid + 256] = (__bf16)(gamma[tid + 256] * xh1 + delta[tid + 256]);
    g[base + tid + 512] = (__bf16)(gamma[tid + 512] * xh2 + delta[tid + 512]);
    xhat[base + tid] = xh0; xhat[base + tid + 256] = xh1; xhat[base + tid + 512] = xh2;
    if (tid == 0) rstd[tok] = r;
  } else if (blk < 5024) {
    const int W4 = DIM * DIM / 4;
    const int X4 = MXI * DIM / 4;
    int i = (blk - 1568) * 256 + tid;
    if (i < W4) {
      float4 v = ((const float4*)wk)[i];
      v4bf o = { (__bf16)v.x, (__bf16)v.y, (__bf16)v.z, (__bf16)v.w };
      *(v4bf*)(wk_bf + 4 * (size_t)i) = o;
    } else if (i < 2 * W4) {
      int j = i - W4;
      float4 v = ((const float4*)wq)[j];
      v4bf o = { (__bf16)v.x, (__bf16)v.y, (__bf16)v.z, (__bf16)v.w };
      *(v4bf*)(wq_bf + 4 * (size_t)j) = o;
    } else if (i < 2 * W4 + X4) {
      int j = i - 2 * W4;
      float4 v = ((const float4*)xi)[j];
      v4bf o = { (__bf16)v.x, (__bf16)v.y, (__bf16)v.z, (__bf16)v.w };
      *(v4bf*)(xi_bf + 4 * (size_t)j) = o;
      int pk = __builtin_amdgcn_cvt_pk_fp8_f32(16.f * v.x, 16.f * v.y, 0, false);
      pk = __builtin_amdgcn_cvt_pk_fp8_f32(16.f * v.z, 16.f * v.w, pk, true);
      xi8[j] = pk;
    }
  } else if (blk < 8480) {
    int job = blk - 5024;
    const float* src; __bf16* dst; int R; float scale; int r0, c0;
    if (job < 576)       { src = wk; dst = wkT; R = DIM; scale = 1.f;  int j = job;        c0 = (j % 24) * 32; r0 = (j / 24) * 32; }
    else if (job < 1152) { src = wq; dst = wqT; R = DIM; scale = 1.f;  int j = job - 576;  c0 = (j % 24) * 32; r0 = (j / 24) * 32; }
    else                 { src = xi; dst = xiT; R = MXI; scale = -1.f; int j = job - 1152; c0 = (j % 24) * 32; r0 = (j / 24) * 32; }
    int tx = tid & 31, ty = tid >> 5;
    for (int rr = ty; rr < 32; rr += 8)
      tt[rr][tx] = src[(size_t)(r0 + rr) * DIM + c0 + tx];
    __syncthreads();
    for (int rr = ty; rr < 32; rr += 8)
      dst[(size_t)(c0 + rr) * R + r0 + tx] = (__bf16)(scale * tt[tx][rr]);
  } else {
    int i = (blk - 8480) * 256 + tid;
    const int PADN = (MPAD - TOK) * DIM;   // 73728
    if (i < PADN) {
      size_t o = (size_t)TOK * DIM + i;
      g[o] = (__bf16)0.f; dq[o] = (__bf16)0.f; dk[o] = (__bf16)0.f;
#pragma unroll
      for (int t = 0; t < 4; t++) {
        gt[(size_t)t * MPAD * DIM + o] = (__bf16)0.f;
        g8[(size_t)t * MPAD * DIM + o] = 0;
      }
    }
  }
}

// ==================================================================
// Dispatch 2: fwd GEMMs: KQb = g @ [wk;wq]^T (156 tiles, M=1664 N=1536)
// | hop base g @ xi^T with relu+energy (312 tiles). grid 468.
// ==================================================================
__global__ __launch_bounds__(256, 4) void fwd_k(
    const __bf16* __restrict__ g, const __bf16* __restrict__ wkq,
    const __bf16* __restrict__ xi_bf, __bf16* __restrict__ KQb,
    __bf16* __restrict__ rh, double* __restrict__ ep)
{
  __shared__ __align__(16) char smem[32768 + 32];
  int blk = blockIdx.x, tid = threadIdx.x;
  v4f acc[4][4];
  acc_zero(acc);
  if (blk < 156) {
    int my = blk / 12, nx = blk - my * 12;
    gemm_core_bf16(smem, g, DIM, wkq, DIM, my * 128, nx * 128, 0, 24, acc, tid);
    epi_store_bf16_ld(acc, KQb, 1536, my * 128, nx * 128, tid);
  } else {
    int j = blk - 156;
    int ry = j / 24, nx = j - ry * 24;
    gemm_core_bf16(smem, g, DIM, xi_bf, DIM, ry * 128, nx * 128, 0, 24, acc, tid);
    epi_relu_energy(acc, rh, MXI, ry * 128, nx * 128, tid,
                    (double*)(smem + 32768), ep + EP_HOPB + ry * 24 + nx);
  }
}

// ==================================================================
// Dispatch 3: base attention core (P store + energy). grid 192 (q-split),
// 512 thr: blk<96 -> half0 (mt 0..6), else half1 (mt 7..12).
// ==================================================================
__global__ __launch_bounds__(512) void battn_k(
    const __bf16* __restrict__ KQb, __bf16* __restrict__ P,
    double* __restrict__ ep)
{
  __shared__ __align__(16) char smem[SM_ATTN];
  int blk = blockIdx.x, tid = threadIdx.x;
  int half = blk >= 96 ? 1 : 0;
  int bh = blk - half * 96;
  int b = bh / HN, h = bh - b * HN;
  dev_stage_kq<512>(smem, KQb + (size_t)(b * SEQ) * 1536 + h * YD, tid);
  double* slot = half ? (ep + EP_A2B + bh) : (ep + bh);
  dev_attn_core<1, 8>(smem, P, (size_t)bh * PAREA, slot,
                      half ? 7 : 0, half ? 13 : 7, tid);
}

// ==================================================================
// Dispatch 4: P -> PT transpose. grid (96, 7, 7).
// ==================================================================
__global__ __launch_bounds__(256) void ptrans_k(
    const __bf16* __restrict__ Pg, __bf16* __restrict__ PTg)
{
  __shared__ __bf16 t[32][33];
  int bh = blockIdx.x;
  int q0 = blockIdx.y * 32, k0 = blockIdx.z * 32;
  int tx = threadIdx.x & 31, ty = threadIdx.x >> 5;
  const __bf16* Pb = Pg + (size_t)bh * PAREA;
  __bf16* PTb = PTg + (size_t)bh * PAREA;
  for (int rr = ty; rr < 32; rr += 8)
    t[rr][tx] = (q0 + rr < PROWS) ? Pb[(size_t)(q0 + rr) * PCOLS + k0 + tx] : (__bf16)0.f;
  __syncthreads();
  for (int rr = ty; rr < 32; rr += 8)
    if (k0 + rr < PROWS)
      PTb[(size_t)(k0 + rr) * PCOLS + q0 + tx] = t[tx][rr];
}

// ==================================================================
// Dispatch 5: bwdA = attn_bwd z0 (96) | z1 (96) | rh@xiT quarters (312).
// grid 504.
// ==================================================================
__global__ __launch_bounds__(256, 4) void bwdA_k(
    const __bf16* __restrict__ KQb,
    const __bf16* __restrict__ P, const __bf16* __restrict__ PT,
    __bf16* __restrict__ dQg, __bf16* __restrict__ dKg,
    const __bf16* __restrict__ rh, const __bf16* __restrict__ xiT,
    float* __restrict__ dGp)
{
  __shared__ __align__(16) char smem[32768];
  int blk = blockIdx.x, tid = threadIdx.x;
  if (blk < 192) {
    int z = blk / 96, bh = blk - z * 96;
    dev_attn_bwd(smem, KQb, P, PT, dQg, dKg, bh, z, tid);
  } else {
    int j = blk - 192;          // 0..311
    int qd = j / 78, jj = j - qd * 78;
    int my = jj / 6, nx = jj - my * 6;
    v4f acc[4][4];
    acc_zero(acc);
    gemm_core_bf16(smem, rh, MXI, xiT, MXI, my * 128, nx * 128, qd * 768, 24, acc, tid);
    epi_store_f32(acc, dGp + (size_t)qd * NPE, my * 128, nx * 128, tid);
  }
}

// ==================================================================
// Dispatch 6: bwdB = dQg@wqT halves | dKg@wkT halves. grid 312.
// ==================================================================
__global__ __launch_bounds__(256, 4) void bwdB_k(
    const __bf16* __restrict__ dQg, const __bf16* __restrict__ wqT,
    const __bf16* __restrict__ dKg, const __bf16* __restrict__ wkT,
    float* __restrict__ dGp)
{
  __shared__ __align__(16) char smem[32768];
  int blk = blockIdx.x, tid = threadIdx.x;
  int z = blk / 156, jj = blk - z * 156;
  int half = jj / 78, j2 = jj - half * 78;
  int my = j2 / 6, nx = j2 - my * 6;
  const __bf16* A = z ? dKg : dQg;
  const __bf16* B = z ? wkT : wqT;
  v4f acc[4][4];
  acc_zero(acc);
  gemm_core_bf16(smem, A, DIM, B, DIM, my * 128, nx * 128, half * 384, 12, acc, tid);
  epi_store_f32(acc, dGp + (size_t)(4 + z * 2 + half) * NPE, my * 128, nx * 128, tid);
}

// ==================================================================
// Dispatch 7: fused LN-backward (sum 8 partials) + trial axpy+LN. grid 1568.
// ==================================================================
__global__ __launch_bounds__(256) void lnbwd_axpy_k(
    const float* __restrict__ dGp,
    const float* __restrict__ xhat, const float* __restrict__ rstd,
    const float* __restrict__ gamma, const float* __restrict__ delta,
    const float* __restrict__ x, float* __restrict__ grad,
    __bf16* __restrict__ gt, unsigned char* __restrict__ g8)
{
  __shared__ float s[8];
  int tok = blockIdx.x, tid = threadIdx.x;
  size_t base = (size_t)tok * DIM;
  float ga0 = gamma[tid], ga1 = gamma[tid + 256], ga2 = gamma[tid + 512];
  float de0 = delta[tid], de1 = delta[tid + 256], de2 = delta[tid + 512];
  float g0 = 0.f, g1 = 0.f, g2 = 0.f;
#pragma unroll
  for (int pi = 0; pi < 8; pi++) {
    const float* p = dGp + (size_t)pi * NPE;
    g0 += p[base + tid];
    g1 += p[base + tid + 256];
    g2 += p[base + tid + 512];
  }
  float dh0 = g0 * ga0, dh1 = g1 * ga1, dh2 = g2 * ga2;
  float xh0 = xhat[base + tid], xh1 = xhat[base + tid + 256], xh2 = xhat[base + tid + 512];
  float s1 = dh0 + dh1 + dh2;
  float s2 = dh0 * xh0 + dh1 * xh1 + dh2 * xh2;
  for (int o = 32; o; o >>= 1) { s1 += __shfl_xor(s1, o, 64); s2 += __shfl_xor(s2, o, 64); }
  if ((tid & 63) == 0) { s[tid >> 6] = s1; s[4 + (tid >> 6)] = s2; }
  __syncthreads();
  float m1 = (s[0] + s[1] + s[2] + s[3]) * (1.0f / DIM);
  float m2 = (s[4] + s[5] + s[6] + s[7]) * (1.0f / DIM);
  float r = rstd[tok];
  float gr0 = r * (dh0 - m1 - xh0 * m2);
  float gr1 = r * (dh1 - m1 - xh1 * m2);
  float gr2 = r * (dh2 - m1 - xh2 * m2);
  grad[base + tid] = gr0; grad[base + tid + 256] = gr1; grad[base + tid + 512] = gr2;
  float xv0 = x[base + tid], xv1 = x[base + tid + 256], xv2 = x[base + tid + 512];
#pragma unroll
  for (int t = 0; t < 4; t++) {
    float lr = 1.0f / (float)(1 << t);
    float v0 = xv0 - lr * gr0, v1 = xv1 - lr * gr1, v2 = xv2 - lr * gr2;
    float sum = v0 + v1 + v2;
    for (int o = 32; o; o >>= 1) sum += __shfl_xor(sum, o, 64);
    __syncthreads();
    if ((tid & 63) == 0) s[tid >> 6] = sum;
    __syncthreads();
    float mu = (s[0] + s[1] + s[2] + s[3]) * (1.0f / DIM);
    float d0 = v0 - mu, d1 = v1 - mu, d2 = v2 - mu;
    float sq = d0 * d0 + d1 * d1 + d2 * d2;
    for (int o = 32; o; o >>= 1) sq += __shfl_xor(sq, o, 64);
    __syncthreads();
    if ((tid & 63) == 0) s[tid >> 6] = sq;
    __syncthreads();
    float var = (s[0] + s[1] + s[2] + s[3]) * (1.0f / DIM);
    float r2 = rsqrtf(var + LN_EPS_F);
    float o0 = ga0 * (d0 * r2) + de0;
    float o1 = ga1 * (d1 * r2) + de1;
    float o2 = ga2 * (d2 * r2) + de2;
    size_t ob = ((size_t)t * MPAD + tok) * DIM;
    gt[ob + tid] = (__bf16)o0; gt[ob + tid + 256] = (__bf16)o1; gt[ob + tid + 512] = (__bf16)o2;
    g8[ob + tid]       = (unsigned char)(__builtin_amdgcn_cvt_pk_fp8_f32(o0, o0, 0, false) & 0xff);
    g8[ob + tid + 256] = (unsigned char)(__builtin_amdgcn_cvt_pk_fp8_f32(o1, o1, 0, false) & 0xff);
    g8[ob + tid + 512] = (unsigned char)(__builtin_amdgcn_cvt_pk_fp8_f32(o2, o2, 0, false) & 0xff);
  }
}

// ==================================================================
// Dispatch 8: merged trial GEMMs at 4 blocks/CU (32800 B LDS). grid 1872:
//   blk in [0,624):    tkq tiles KQt[t] = gt[t] @ [wk;wq]^T (XCD-swizzled)
//   blk in [624,1872): MX fp8 trial hopfield, ONE job per block
// 1024 resident slots (2x the 66KB pairing) -> halved occupancy floor.
// ==================================================================
__global__ __launch_bounds__(256, 4) void tkqhop_k(
    const __bf16* __restrict__ gt, const __bf16* __restrict__ wkq,
    __bf16* __restrict__ KQt,
    const unsigned char* __restrict__ g8, const unsigned char* __restrict__ xi8,
    double* __restrict__ ep)
{
  __shared__ __align__(16) char smem[32800];
  int blk = blockIdx.x, tid = threadIdx.x;
  if (blk < 624) {
    int swz = (blk & 7) * 78 + (blk >> 3);
    int t = swz / 156, j = swz - t * 156;
    int my = j / 12, nx = j - my * 12;
    v4f acc[4][4];
    acc_zero(acc);
    gemm_core_bf16(smem, gt + (size_t)t * MPAD * DIM, DIM, wkq, DIM,
                   my * 128, nx * 128, 0, 24, acc, tid);
    epi_store_bf16_ld(acc, KQt + (size_t)t * MPAD * 1536, 1536,
                      my * 128, nx * 128, tid);
  } else {
    int hid = blk - 624;                  // 0..1247; 624%8==0 keeps hid&7==blk&7
    int xcd = hid & 7, q = hid >> 3;      // q: 0..155
    int nx = xcd * 3 + q % 3;             // 0..23
    int my = q / 3;                       // 0..51
    dev_gemm_mx8(smem, g8, xi8, ep, my, nx, tid);
  }
}

// ==================================================================
// Dispatch 9: trial attention core on precomputed KQt. grid 768
// (q-split), 512 thr, XCD-swizzled: xcd owns 4 (b,t) slabs.
// ==================================================================
__global__ __launch_bounds__(512) void tattn_k(
    const __bf16* __restrict__ KQt, double* __restrict__ ep)
{
  __shared__ __align__(16) char smem[SM_ATTN];
  int id = blockIdx.x, tid = threadIdx.x;
  int xcd = id & 7, q = id >> 3;          // q: 0..95
  int bt = xcd * 4 + (q & 3);             // 0..31
  int rest = q >> 2;                      // 0..23
  int h = rest >> 1, half = rest & 1;
  int b = bt >> 2, t = bt & 3;
  int bh = b * HN + h;
  const __bf16* Ksrc = KQt + (size_t)t * MPAD * 1536 + (size_t)(b * SEQ) * 1536 + h * YD;
  dev_stage_kq<512>(smem, Ksrc, tid);
  double* slot = half ? (ep + EP_A2T + t * 96 + bh) : (ep + (t + 1) * 96 + bh);
  dev_attn_core<0, 8>(smem, (__bf16*)nullptr, 0, slot,
                      half ? 7 : 0, half ? 13 : 7, tid);
}

// ==================================================================
// Dispatch 10: fused reduce+choose+update. grid 624 (grid-stride).
// ==================================================================
__global__ __launch_bounds__(256) void update_k(
    const float* __restrict__ x, const float* __restrict__ grad,
    const double* __restrict__ ep, float* __restrict__ out, int n4)
{
  __shared__ double sm[4];
  __shared__ float chs;
  int tid = threadIdx.x;
  double e[5];
  for (int s = 0; s < 5; s++) {
    double acc = 0.0;
    int a0 = 96 * s;
    int a2 = (s == 0) ? EP_A2B : EP_A2T + 96 * (s - 1);
    for (int i = tid; i < 96; i += 256) acc += ep[a0 + i] + ep[a2 + i];
    int b0 = (s == 0) ? EP_HOPB : EP_HOPT + 312 * (s - 1);
    for (int i = tid; i < 312; i += 256) acc += ep[b0 + i];
    for (int o = 32; o; o >>= 1) acc += __shfl_xor(acc, o, 64);
    if ((tid & 63) == 0) sm[tid >> 6] = acc;
    __syncthreads();
    e[s] = (sm[0] + sm[1]) + (sm[2] + sm[3]);
    __syncthreads();
  }
  if (tid == 0) {
    double e0 = e[0];
    float c = 0.0625f;
    if (e[4] < e0) c = 0.125f;
    if (e[3] < e0) c = 0.25f;
    if (e[2] < e0) c = 0.5f;
    if (e[1] < e0) c = 1.0f;
    chs = c;
  }
  __syncthreads();
  float lr = chs;
  for (int i = blockIdx.x * 256 + tid; i < n4; i += gridDim.x * 256) {
    const float4 xv = ((const float4*)x)[i];
    const float4 gv = ((const float4*)grad)[i];
    float4 o;
    o.x = xv.x - lr * gv.x; o.y = xv.y - lr * gv.y;
    o.z = xv.z - lr * gv.z; o.w = xv.w - lr * gv.w;
    ((float4*)out)[i] = o;
  }
}

// ------------------------------------------------------------------
extern "C" void kernel_launch(void* const* d_in, const int* in_sizes, int n_in,
                              void* d_out, int out_size, void* d_ws, size_t ws_size,
                              hipStream_t stream)
{
  const float* x     = (const float*)d_in[0];
  const float* gamma = (const float*)d_in[1];
  const float* delta = (const float*)d_in[2];
  const float* wk    = (const float*)d_in[3];
  const float* wq    = (const float*)d_in[4];
  const float* xi    = (const float*)d_in[5];
  float* out = (float*)d_out;

  const size_t NE = (size_t)TOK * DIM;
  const size_t NP = NPE;

  double* eparts = (double*)d_ws;                // EP_TOTAL doubles
  float* fp = (float*)(eparts + EP_TOTAL + 8);
  float* xhat = fp;  fp += NE;
  float* grad = fp;  fp += NE;
  float* rstd = fp;  fp += TOK;
  fp += 16;
  float* dGp = (float*)(((uintptr_t)fp + 15) & ~(uintptr_t)15);   // 8 * NP floats
  __bf16* bp = (__bf16*)(dGp + 8 * NP);
  __bf16* g_bf   = bp;  bp += NP;
  __bf16* g_tr   = bp;  bp += 4 * NP;
  __bf16* KQb    = bp;  bp += 2 * NP;   // base K|Q [MPAD][1536]
  __bf16* dQg_bf = bp;  bp += NP;
  __bf16* dKg_bf = bp;  bp += NP;
  __bf16* rh_bf  = bp;  bp += (size_t)MPAD * MXI;
  __bf16* wk_bf  = bp;  bp += (size_t)DIM * DIM;
  __bf16* wq_bf  = bp;  bp += (size_t)DIM * DIM;
  __bf16* wkT_bf = bp;  bp += (size_t)DIM * DIM;
  __bf16* wqT_bf = bp;  bp += (size_t)DIM * DIM;
  __bf16* xi_bf  = bp;  bp += (size_t)MXI * DIM;
  __bf16* xiT_bf = bp;  bp += (size_t)DIM * MXI;
  __bf16* P_bf   = bp;  bp += (size_t)96 * PAREA;
  __bf16* PT_bf  = bp;  bp += (size_t)96 * PAREA;
  unsigned char* g8  = (unsigned char*)bp;  bp += 2 * NP;              // 4*NP bytes
  unsigned char* xi8 = (unsigned char*)bp;  bp += (size_t)MXI * DIM / 2;

  // trial K/Q buffer [4][MPAD][1536] bf16 = 20.4 MB, aliased onto dGp
  // (dGp is dead after lnbwd_axpy_k; 8*NP floats = 40.9 MB >= 20.4 MB)
  __bf16* KQt = (__bf16*)dGp;

  const int n4 = (int)(NE / 4);
  dim3 blk(256);

  // 1. prep
  hipLaunchKernelGGL(prep_k, dim3(8768), blk, 0, stream,
                     x, gamma, delta, wk, wq, xi,
                     g_bf, xhat, rstd, wk_bf, wq_bf, xi_bf, (int*)xi8,
                     wkT_bf, wqT_bf, xiT_bf, g_tr, g8, dQg_bf, dKg_bf);
  // 2. fwd GEMMs: base KQ build + hop base (wk_bf/wq_bf contiguous -> N=1536)
  hipLaunchKernelGGL(fwd_k, dim3(468), blk, 0, stream,
                     g_bf, wk_bf, xi_bf, KQb, rh_bf, eparts);
  // 3. base attn core (P + energy), q-split
  hipLaunchKernelGGL(battn_k, dim3(192), dim3(512), 0, stream,
                     KQb, P_bf, eparts);
  // 4. ptrans
  hipLaunchKernelGGL(ptrans_k, dim3(96, 7, 7), blk, 0, stream, P_bf, PT_bf);
  // 5. attn_bwd + rh@xiT quarters
  hipLaunchKernelGGL(bwdA_k, dim3(504), blk, 0, stream,
                     KQb, P_bf, PT_bf, dQg_bf, dKg_bf, rh_bf, xiT_bf, dGp);
  // 6. dQg@wqT + dKg@wkT (K-halved)
  hipLaunchKernelGGL(bwdB_k, dim3(312), blk, 0, stream,
                     dQg_bf, wqT_bf, dKg_bf, wkT_bf, dGp);
  // 7. ln_bwd + trial axpy/LN fused
  hipLaunchKernelGGL(lnbwd_axpy_k, dim3(TOK), blk, 0, stream,
                     dGp, xhat, rstd, gamma, delta, x, grad, g_tr, g8);
  // 8. merged trial GEMMs: tkq + single-buffered MX fp8 hop (4 blocks/CU)
  hipLaunchKernelGGL(tkqhop_k, dim3(1872), blk, 0, stream,
                     g_tr, wk_bf, KQt, g8, xi8, eparts);
  // 9. trial attention core (q-split, XCD-swizzled)
  hipLaunchKernelGGL(tattn_k, dim3(768), dim3(512), 0, stream, KQt, eparts);
  // 10. reduce + choose + update
  hipLaunchKernelGGL(update_k, dim3(624), blk, 0, stream,
                     x, grad, eparts, out, n4);
}

// Round 7
// 240.499 us; speedup vs baseline: 1.1471x; 1.1471x over previous
//
#include <hip/hip_runtime.h>
#include <math.h>

#define TOK 1568      // B*N = 8*196
#define MPAD 1664     // 13 * 128
#define DIM 768
#define HN 12
#define SEQ 196
#define YD 64
#define MXI 3072
#define BETA_F 0.125f
#define INV_BETA 8.0f
#define LN_EPS_F 1e-5f

// P/PT padded geometry: rows 208 (13*16), cols 224 (7*32)
#define PROWS 208
#define PCOLS 224
#define PAREA (PROWS * PCOLS)

// energy partials (doubles):
// attn ver*96+bh, ver 0..4 -> [0,480)   (bank A / half0)
// hop base [480,792) ; hop trial t*312 -> [792,2040)
// trial attn bank B (half1): 2040 + t*96 + bh -> [2040,2424)
// base attn bank B (half1): 2424 + bh -> [2424,2520)
#define EP_HOPB 480
#define EP_HOPT 792
#define EP_A2T 2040
#define EP_A2B 2424
#define EP_TOTAL 2520

#define NPE ((size_t)MPAD * DIM)

// attn-core LDS layout (bytes): Ks[208*72] | Qs[208*72] | er[8]
#define OFF_QS 29952
#define OFF_ER 59904
#define SM_ATTN 59968

typedef __bf16 v8bf __attribute__((ext_vector_type(8)));
typedef __bf16 v4bf __attribute__((ext_vector_type(4)));
typedef float  v4f  __attribute__((ext_vector_type(4)));
typedef int    v4i  __attribute__((ext_vector_type(4)));
typedef int    v8i  __attribute__((ext_vector_type(8)));

__device__ __forceinline__ v8bf zero8() {
  v8bf v = { (__bf16)0.f, (__bf16)0.f, (__bf16)0.f, (__bf16)0.f,
             (__bf16)0.f, (__bf16)0.f, (__bf16)0.f, (__bf16)0.f };
  return v;
}

// ------------------------------------------------------------------
// Stage one 128x32 bf16 tile into LDS (global_load_lds width=16).
// ------------------------------------------------------------------
__device__ __forceinline__ void stage_tile(
    const __bf16* __restrict__ G, int ldK, int r0, int k0,
    __bf16* S, int tid, int w)
{
#pragma unroll
  for (int r = 0; r < 2; r++) {
    int ch = (r << 8) + tid;
    int row = ch >> 2;
    int col = (ch & 3) ^ ((row >> 1) & 3);
    __builtin_amdgcn_global_load_lds(
        (__attribute__((address_space(1))) uint32_t*)(G + (size_t)(r0 + row) * ldK + k0 + (col << 3)),
        (__attribute__((address_space(3))) uint32_t*)(S + (r << 11) + (w << 9)),
        16, 0, 0);
  }
}

// ------------------------------------------------------------------
// bf16 MFMA GEMM core: acc += A[m0:+128, kbase:+nk*32] @ B[n0:+128]^T
// smem: As 2x4096 bf16 | Bs 2x4096 bf16 (32768 B)
// ------------------------------------------------------------------
__device__ __forceinline__ void gemm_core_bf16(
    char* smem, const __bf16* __restrict__ A, int ldA,
    const __bf16* __restrict__ B, int ldB,
    int m0, int n0, int kbase, int nk, v4f acc[4][4], int tid)
{
  __bf16* As = (__bf16*)smem;
  __bf16* Bs = (__bf16*)smem + 8192;
  int lane = tid & 63, w = tid >> 6;
  int wm = (w & 1) << 6, wn = (w >> 1) << 6;
  stage_tile(A, ldA, m0, kbase, As, tid, w);
  stage_tile(B, ldB, n0, kbase, Bs, tid, w);
  for (int kt = 0; kt < nk; kt++) {
    __syncthreads();
    int nxt = kt + 1;
    if (nxt < nk) {
      stage_tile(A, ldA, m0, kbase + (nxt << 5), As + ((nxt & 1) << 12), tid, w);
      stage_tile(B, ldB, n0, kbase + (nxt << 5), Bs + ((nxt & 1) << 12), tid, w);
    }
    const __bf16* Ac = As + ((kt & 1) << 12);
    const __bf16* Bc = Bs + ((kt & 1) << 12);
    int mrow = lane & 15, q = lane >> 4;
    v8bf af[4], bfr[4];
#pragma unroll
    for (int i = 0; i < 4; i++) {
      int rA = wm + (i << 4) + mrow;
      int rB = wn + (i << 4) + mrow;
      af[i]  = *(const v8bf*)(Ac + rA * 32 + ((q ^ ((rA >> 1) & 3)) << 3));
      bfr[i] = *(const v8bf*)(Bc + rB * 32 + ((q ^ ((rB >> 1) & 3)) << 3));
    }
#pragma unroll
    for (int i = 0; i < 4; i++)
#pragma unroll
      for (int j = 0; j < 4; j++)
        acc[i][j] = __builtin_amdgcn_mfma_f32_16x16x32_bf16(af[i], bfr[j], acc[i][j], 0, 0, 0);
  }
}

__device__ __forceinline__ void acc_zero(v4f acc[4][4]) {
  v4f z = {0.f, 0.f, 0.f, 0.f};
#pragma unroll
  for (int i = 0; i < 4; i++)
#pragma unroll
    for (int j = 0; j < 4; j++) acc[i][j] = z;
}

__device__ __forceinline__ void epi_store_f32(
    v4f acc[4][4], float* C, int m0, int n0, int tid)
{
  int lane = tid & 63, w = tid >> 6;
  int wm = (w & 1) << 6, wn = (w >> 1) << 6;
  int quad = lane >> 4, ncol = lane & 15;
#pragma unroll
  for (int i = 0; i < 4; i++)
#pragma unroll
    for (int j = 0; j < 4; j++) {
      int row = m0 + wm + (i << 4) + (quad << 2);
      int col = n0 + wn + (j << 4) + ncol;
#pragma unroll
      for (int r = 0; r < 4; r++)
        C[(size_t)(row + r) * DIM + col] = acc[i][j][r];
    }
}

// bf16 store epilogue with arbitrary ldC
__device__ __forceinline__ void epi_store_bf16_ld(
    v4f acc[4][4], __bf16* C, int ldC, int m0, int n0, int tid)
{
  int lane = tid & 63, w = tid >> 6;
  int wm = (w & 1) << 6, wn = (w >> 1) << 6;
  int quad = lane >> 4, ncol = lane & 15;
#pragma unroll
  for (int i = 0; i < 4; i++)
#pragma unroll
    for (int j = 0; j < 4; j++) {
      int row = m0 + wm + (i << 4) + (quad << 2);
      int col = n0 + wn + (j << 4) + ncol;
#pragma unroll
      for (int r = 0; r < 4; r++)
        C[(size_t)(row + r) * ldC + col] = (__bf16)acc[i][j][r];
    }
}

__device__ __forceinline__ void epi_relu_energy(
    v4f acc[4][4], __bf16* C, int N, int m0, int n0, int tid,
    double* ered, double* ep_slot)
{
  int lane = tid & 63, w = tid >> 6;
  int wm = (w & 1) << 6, wn = (w >> 1) << 6;
  int quad = lane >> 4, ncol = lane & 15;
  float e = 0.f;
#pragma unroll
  for (int i = 0; i < 4; i++)
#pragma unroll
    for (int j = 0; j < 4; j++) {
      int row = m0 + wm + (i << 4) + (quad << 2);
      int col = n0 + wn + (j << 4) + ncol;
#pragma unroll
      for (int r = 0; r < 4; r++) {
        float v = acc[i][j][r];
        v = v > 0.f ? v : 0.f;
        e += v * v;
        C[(size_t)(row + r) * N + col] = (__bf16)v;
      }
    }
  for (int o = 32; o; o >>= 1) e += __shfl_xor(e, o, 64);
  if (lane == 0) ered[w] = (double)e;
  __syncthreads();
  if (tid == 0)
    *ep_slot = -0.5 * ((ered[0] + ered[1]) + (ered[2] + ered[3]));
}

// ------------------------------------------------------------------
// MX fp8 (e4m3, unit scales) GEMM, energy only (trial hopfield).
// K-step 128 per MFMA (mfma_scale 16x16x128), BK=128 staging.
// DOUBLE-buffered: As 2x16384 | Bs 2x16384 | ered 32  (65568 B)
// Needs (256,2) register budget: 64 VGPR operands + 64 AGPR acc.
// ------------------------------------------------------------------
__device__ __forceinline__ void stage_mx(
    const unsigned char* __restrict__ A0, const unsigned char* __restrict__ B0,
    unsigned char* As, unsigned char* Bs, int m0, int n0, int k0, int tid)
{
#pragma unroll
  for (int rr = 0; rr < 4; rr++) {
    int ch = (rr << 8) + tid;          // chunk 0..1023
    int row = ch >> 3;                 // 0..127
    int gc = ((ch & 7) ^ (row & 7)) << 4;
    int dst = (rr << 12) + ((tid >> 6) << 10);   // + lane*16 by HW
    __builtin_amdgcn_global_load_lds(
        (__attribute__((address_space(1))) uint32_t*)(A0 + (size_t)(m0 + row) * DIM + k0 + gc),
        (__attribute__((address_space(3))) uint32_t*)(As + dst), 16, 0, 0);
    __builtin_amdgcn_global_load_lds(
        (__attribute__((address_space(1))) uint32_t*)(B0 + (size_t)(n0 + row) * DIM + k0 + gc),
        (__attribute__((address_space(3))) uint32_t*)(Bs + dst), 16, 0, 0);
  }
}

__device__ __forceinline__ void dev_gemm_mx8(
    char* smem, const unsigned char* __restrict__ A0,
    const unsigned char* __restrict__ B0, double* __restrict__ ep,
    int my, int nx, int tid)
{
  unsigned char* As = (unsigned char*)smem;           // 2 x 16384
  unsigned char* Bs = (unsigned char*)smem + 32768;   // 2 x 16384
  double* ered = (double*)(smem + 65536);
  int lane = tid & 63, w = tid >> 6;
  int wm = (w & 1) << 6, wn = (w >> 1) << 6;
  int m0 = my * 128, n0 = nx * 128;

  v4f acc[4][4];
  acc_zero(acc);

  const int nk = 6;   // 768 / 128
  stage_mx(A0, B0, As, Bs, m0, n0, 0, tid);
  for (int kt = 0; kt < nk; kt++) {
    __syncthreads();
    int nxt = kt + 1;
    if (nxt < nk)
      stage_mx(A0, B0, As + ((nxt & 1) << 14), Bs + ((nxt & 1) << 14),
               m0, n0, nxt << 7, tid);
    const unsigned char* Ac = As + ((kt & 1) << 14);
    const unsigned char* Bc = Bs + ((kt & 1) << 14);
    int mrow = lane & 15, qs = lane >> 4;
    v8i af[4], bfr[4];
#pragma unroll
    for (int i = 0; i < 4; i++) {
      int rA = wm + (i << 4) + mrow;
      int rB = wn + (i << 4) + mrow;
      int sa = rA & 7, sb = rB & 7;
      v4i alo = *(const v4i*)(Ac + rA * 128 + ((((qs << 1)) ^ sa) << 4));
      v4i ahi = *(const v4i*)(Ac + rA * 128 + ((((qs << 1) | 1) ^ sa) << 4));
      v4i blo = *(const v4i*)(Bc + rB * 128 + ((((qs << 1)) ^ sb) << 4));
      v4i bhi = *(const v4i*)(Bc + rB * 128 + ((((qs << 1) | 1) ^ sb) << 4));
      af[i]  = __builtin_shufflevector(alo, ahi, 0, 1, 2, 3, 4, 5, 6, 7);
      bfr[i] = __builtin_shufflevector(blo, bhi, 0, 1, 2, 3, 4, 5, 6, 7);
    }
#pragma unroll
    for (int i = 0; i < 4; i++)
#pragma unroll
      for (int j = 0; j < 4; j++)
        acc[i][j] = __builtin_amdgcn_mfma_scale_f32_16x16x128_f8f6f4(
            af[i], bfr[j], acc[i][j], 0, 0, 0, 127, 0, 127);
  }

  float e = 0.f;
#pragma unroll
  for (int i = 0; i < 4; i++)
#pragma unroll
    for (int j = 0; j < 4; j++)
#pragma unroll
      for (int r = 0; r < 4; r++) {
        float v = acc[i][j][r];
        v = v > 0.f ? v : 0.f;
        e += v * v;
      }
  for (int o = 32; o; o >>= 1) e += __shfl_xor(e, o, 64);
  if (lane == 0) ered[w] = (double)e;
  __syncthreads();
  if (tid == 0) {
    double tot = (ered[0] + ered[1]) + (ered[2] + ered[3]);
    int tt = my / 13, ry = my - tt * 13;
    ep[EP_HOPT + tt * 312 + ry * 24 + nx] = (-0.5 / 256.0) * tot;
  }
}

// ------------------------------------------------------------------
// Attention core on prefilled Ks/Qs (stride 72). NW = waves per block.
// Processes mt in [mt_begin, mt_end) strided by NW.
// SP=1: store P AND PT (transposed) + energy. PT pre-offset to bh slab.
// ------------------------------------------------------------------
template <int SP, int NW>
__device__ __forceinline__ void dev_attn_core(
    char* smem, __bf16* __restrict__ P, __bf16* __restrict__ PT, size_t Pbase,
    double* __restrict__ ep_slot, int mt_begin, int mt_end, int tid)
{
  __bf16* Ks = (__bf16*)smem;
  __bf16* Qs = (__bf16*)(smem + OFF_QS);
  double* er = (double*)(smem + OFF_ER);
  int lane = tid & 63, w = tid >> 6;
  int mrow = lane & 15, quad = lane >> 4, ncol = mrow;
  int ksel = quad * 8;
  v4f zero = {0.f, 0.f, 0.f, 0.f};
  double eacc = 0.0;

  for (int mt = mt_begin + w; mt < mt_end; mt += NW) {
    int m0 = mt * 16;
    v8bf af0 = *(const v8bf*)(Qs + (m0 + mrow) * 72 + ksel);
    v8bf af1 = *(const v8bf*)(Qs + (m0 + mrow) * 72 + 32 + ksel);
    v4f acc[13];
#pragma unroll
    for (int j = 0; j < 13; j++) {
      v8bf bf0 = *(const v8bf*)(Ks + (j * 16 + mrow) * 72 + ksel);
      v8bf bf1 = *(const v8bf*)(Ks + (j * 16 + mrow) * 72 + 32 + ksel);
      v4f t = __builtin_amdgcn_mfma_f32_16x16x32_bf16(af0, bf0, zero, 0, 0, 0);
      acc[j] = __builtin_amdgcn_mfma_f32_16x16x32_bf16(af1, bf1, t, 0, 0, 0);
    }
    float mx[4] = {-1e30f, -1e30f, -1e30f, -1e30f};
#pragma unroll
    for (int j = 0; j < 13; j++) {
      bool colv = (j < 12) || (ncol < 4);
#pragma unroll
      for (int r = 0; r < 4; r++) {
        float sv = colv ? BETA_F * acc[j][r] : -1e30f;
        acc[j][r] = sv;
        mx[r] = fmaxf(mx[r], sv);
      }
    }
#pragma unroll
    for (int o = 1; o < 16; o <<= 1)
#pragma unroll
      for (int r = 0; r < 4; r++) mx[r] = fmaxf(mx[r], __shfl_xor(mx[r], o, 64));
    float zr[4] = {0.f, 0.f, 0.f, 0.f};
#pragma unroll
    for (int j = 0; j < 13; j++)
#pragma unroll
      for (int r = 0; r < 4; r++) {
        float t = (acc[j][r] > -1e29f) ? expf(acc[j][r] - mx[r]) : 0.f;
        acc[j][r] = t;
        zr[r] += t;
      }
#pragma unroll
    for (int o = 1; o < 16; o <<= 1)
#pragma unroll
      for (int r = 0; r < 4; r++) zr[r] += __shfl_xor(zr[r], o, 64);
    if (ncol == 0) {
#pragma unroll
      for (int r = 0; r < 4; r++) {
        int q = m0 + quad * 4 + r;
        if (q < SEQ) eacc += (double)(mx[r] + logf(zr[r]));
      }
    }
    if (SP) {
      float inv[4];
#pragma unroll
      for (int r = 0; r < 4; r++) inv[r] = 1.f / zr[r];
      size_t Pb = Pbase + (size_t)(m0 + quad * 4) * PCOLS;
#pragma unroll
      for (int j = 0; j < 13; j++)
#pragma unroll
        for (int r = 0; r < 4; r++) {
          int q = m0 + quad * 4 + r;
          float pv = (q < SEQ) ? acc[j][r] * inv[r] : 0.f;
          __bf16 pb = (__bf16)pv;
          P[Pb + (size_t)r * PCOLS + j * 16 + ncol] = pb;
          PT[(size_t)(j * 16 + ncol) * PCOLS + q] = pb;
        }
#pragma unroll
      for (int r = 0; r < 4; r++)
        P[Pb + (size_t)r * PCOLS + 208 + ncol] = (__bf16)0.f;
    }
  }
  for (int o = 32; o; o >>= 1) eacc += __shfl_xor(eacc, o, 64);
  if (lane == 0) er[w] = eacc;
  __syncthreads();
  if (tid == 0) {
    double s = 0.0;
#pragma unroll
    for (int i = 0; i < NW; i++) s += er[i];
    *ep_slot = -(double)INV_BETA * s;
  }
}

// stage K/Q [208x64] slabs from KQ buffer (ld 1536) into Ks/Qs (stride 72)
template <int NT>
__device__ __forceinline__ void dev_stage_kq(
    char* smem, const __bf16* __restrict__ Ksrc, int tid)
{
  const __bf16* Qsrc = Ksrc + 768;
  __bf16* Ks = (__bf16*)smem;
  __bf16* Qs = (__bf16*)(smem + OFF_QS);
  for (int i = tid; i < PROWS * 8; i += NT) {
    int row = i >> 3, c = (i & 7) << 3;
    v8bf kv = zero8(), qv = zero8();
    if (row < SEQ) {
      kv = *(const v8bf*)(Ksrc + (size_t)row * 1536 + c);
      qv = *(const v8bf*)(Qsrc + (size_t)row * 1536 + c);
    }
    *(v8bf*)(Ks + row * 72 + c) = kv;
    *(v8bf*)(Qs + row * 72 + c) = qv;
  }
  __syncthreads();
}

// ------------------------------------------------------------------
// MFMA attention backward one side. smem: BT 29696 B.
// z=0: dQ = -(P@K); z=1: dK = -(PT@Q).  K/Q read from KQb (ld 1536).
// ------------------------------------------------------------------
__device__ __forceinline__ void dev_attn_bwd(
    char* smem, const __bf16* __restrict__ KQb,
    const __bf16* __restrict__ Pg, const __bf16* __restrict__ PTg,
    __bf16* __restrict__ dQg, __bf16* __restrict__ dKg,
    int bh, int z, int tid)
{
  __bf16* BT = (__bf16*)smem;   // 64 x 232
  int b = bh / HN, h = bh - b * HN;
  const __bf16* Bsrc = KQb + (size_t)(b * SEQ) * 1536 + (z ? 768 : 0) + h * YD;
  const __bf16* Asrc = (z ? PTg : Pg) + (size_t)bh * PAREA;
  __bf16* Dst = (z ? dKg : dQg) + (size_t)(b * SEQ) * DIM + h * YD;
  for (int i = tid; i < 64 * 232 / 8; i += 256) ((v8bf*)BT)[i] = zero8();
  __syncthreads();
  for (int i = tid; i < SEQ * 8; i += 256) {
    int k = i >> 3, c = i & 7;
    v8bf v = *(const v8bf*)(Bsrc + (size_t)k * 1536 + c * 8);
#pragma unroll
    for (int e = 0; e < 8; e++) BT[(c * 8 + e) * 232 + k] = v[e];
  }
  __syncthreads();

  int lane = tid & 63, w = tid >> 6;
  int mrow = lane & 15, quad = lane >> 4, ncol = mrow;
  int ksel = quad * 8;
  for (int mt = w; mt < 13; mt += 4) {
    int m0 = mt * 16;
    v4f acc[4];
    v4f zero = {0.f, 0.f, 0.f, 0.f};
#pragma unroll
    for (int n = 0; n < 4; n++) acc[n] = zero;
    v8bf afc = *(const v8bf*)(Asrc + (size_t)(m0 + mrow) * PCOLS + ksel);
#pragma unroll
    for (int s = 0; s < 7; s++) {
      v8bf afn = (s < 6)
          ? *(const v8bf*)(Asrc + (size_t)(m0 + mrow) * PCOLS + (s + 1) * 32 + ksel)
          : zero8();
#pragma unroll
      for (int n = 0; n < 4; n++) {
        v8bf bf = *(const v8bf*)(BT + (n * 16 + mrow) * 232 + s * 32 + ksel);
        acc[n] = __builtin_amdgcn_mfma_f32_16x16x32_bf16(afc, bf, acc[n], 0, 0, 0);
      }
      afc = afn;
    }
    int row = m0 + quad * 4;
#pragma unroll
    for (int n = 0; n < 4; n++)
#pragma unroll
      for (int r = 0; r < 4; r++)
        if (row + r < SEQ)
          Dst[(size_t)(row + r) * DIM + n * 16 + ncol] = (__bf16)(-acc[n][r]);
  }
}

// ==================================================================
// Dispatch 1: prep = ln_fwd(1568) | cvtall(3456) | cvtT(3456) | init(288)
// ==================================================================
__global__ __launch_bounds__(256) void prep_k(
    const float* __restrict__ x, const float* __restrict__ gamma,
    const float* __restrict__ delta, const float* __restrict__ wk,
    const float* __restrict__ wq, const float* __restrict__ xi,
    __bf16* __restrict__ g, float* __restrict__ xhat, float* __restrict__ rstd,
    __bf16* __restrict__ wk_bf, __bf16* __restrict__ wq_bf,
    __bf16* __restrict__ xi_bf, int* __restrict__ xi8,
    __bf16* __restrict__ wkT, __bf16* __restrict__ wqT, __bf16* __restrict__ xiT,
    __bf16* __restrict__ gt, unsigned char* __restrict__ g8,
    __bf16* __restrict__ dq, __bf16* __restrict__ dk)
{
  __shared__ float s[4];
  __shared__ float tt[32][33];
  int blk = blockIdx.x, tid = threadIdx.x;
  if (blk < 1568) {
    int tok = blk;
    const float* xp = x + (size_t)tok * DIM;
    float v0 = xp[tid], v1 = xp[tid + 256], v2 = xp[tid + 512];
    float sum = v0 + v1 + v2;
    for (int o = 32; o; o >>= 1) sum += __shfl_xor(sum, o, 64);
    if ((tid & 63) == 0) s[tid >> 6] = sum;
    __syncthreads();
    float mu = (s[0] + s[1] + s[2] + s[3]) * (1.0f / DIM);
    __syncthreads();
    float d0 = v0 - mu, d1 = v1 - mu, d2 = v2 - mu;
    float sq = d0 * d0 + d1 * d1 + d2 * d2;
    for (int o = 32; o; o >>= 1) sq += __shfl_xor(sq, o, 64);
    if ((tid & 63) == 0) s[tid >> 6] = sq;
    __syncthreads();
    float var = (s[0] + s[1] + s[2] + s[3]) * (1.0f / DIM);
    float r = rsqrtf(var + LN_EPS_F);
    float xh0 = d0 * r, xh1 = d1 * r, xh2 = d2 * r;
    size_t base = (size_t)tok * DIM;
    g[base + tid]       = (__bf16)(gamma[tid] * xh0 + delta[tid]);
    g[base + tid + 256] = (__bf16)(gamma[tid + 256] * xh1 + delta[tid + 256]);
    g[base + tid + 512] = (__bf16)(gamma[tid + 512] * xh2 + delta[tid + 512]);
    xhat[base + tid] = xh0; xhat[base + tid + 256] = xh1; xhat[base + tid + 512] = xh2;
    if (tid == 0) rstd[tok] = r;
  } else if (blk < 5024) {
    const int W4 = DIM * DIM / 4;
    const int X4 = MXI * DIM / 4;
    int i = (blk - 1568) * 256 + tid;
    if (i < W4) {
      float4 v = ((const float4*)wk)[i];
      v4bf o = { (__bf16)v.x, (__bf16)v.y, (__bf16)v.z, (__bf16)v.w };
      *(v4bf*)(wk_bf + 4 * (size_t)i) = o;
    } else if (i < 2 * W4) {
      int j = i - W4;
      float4 v = ((const float4*)wq)[j];
      v4bf o = { (__bf16)v.x, (__bf16)v.y, (__bf16)v.z, (__bf16)v.w };
      *(v4bf*)(wq_bf + 4 * (size_t)j) = o;
    } else if (i < 2 * W4 + X4) {
      int j = i - 2 * W4;
      float4 v = ((const float4*)xi)[j];
      v4bf o = { (__bf16)v.x, (__bf16)v.y, (__bf16)v.z, (__bf16)v.w };
      *(v4bf*)(xi_bf + 4 * (size_t)j) = o;
      int pk = __builtin_amdgcn_cvt_pk_fp8_f32(16.f * v.x, 16.f * v.y, 0, false);
      pk = __builtin_amdgcn_cvt_pk_fp8_f32(16.f * v.z, 16.f * v.w, pk, true);
      xi8[j] = pk;
    }
  } else if (blk < 8480) {
    int job = blk - 5024;
    const float* src; __bf16* dst; int R; float scale; int r0, c0;
    if (job < 576)       { src = wk; dst = wkT; R = DIM; scale = 1.f;  int j = job;        c0 = (j % 24) * 32; r0 = (j / 24) * 32; }
    else if (job < 1152) { src = wq; dst = wqT; R = DIM; scale = 1.f;  int j = job - 576;  c0 = (j % 24) * 32; r0 = (j / 24) * 32; }
    else                 { src = xi; dst = xiT; R = MXI; scale = -1.f; int j = job - 1152; c0 = (j % 24) * 32; r0 = (j / 24) * 32; }
    int tx = tid & 31, ty = tid >> 5;
    for (int rr = ty; rr < 32; rr += 8)
      tt[rr][tx] = src[(size_t)(r0 + rr) * DIM + c0 + tx];
    __syncthreads();
    for (int rr = ty; rr < 32; rr += 8)
      dst[(size_t)(c0 + rr) * R + r0 + tx] = (__bf16)(scale * tt[tx][rr]);
  } else {
    int i = (blk - 8480) * 256 + tid;
    const int PADN = (MPAD - TOK) * DIM;   // 73728
    if (i < PADN) {
      size_t o = (size_t)TOK * DIM + i;
      g[o] = (__bf16)0.f; dq[o] = (__bf16)0.f; dk[o] = (__bf16)0.f;
#pragma unroll
      for (int t = 0; t < 4; t++) {
        gt[(size_t)t * MPAD * DIM + o] = (__bf16)0.f;
        g8[(size_t)t * MPAD * DIM + o] = 0;
      }
    }
  }
}

// ==================================================================
// Dispatch 2: fwd GEMMs: KQb = g @ [wk;wq]^T (156 tiles, M=1664 N=1536)
// | hop base g @ xi^T with relu+energy (312 tiles). grid 468.
// ==================================================================
__global__ __launch_bounds__(256, 4) void fwd_k(
    const __bf16* __restrict__ g, const __bf16* __restrict__ wkq,
    const __bf16* __restrict__ xi_bf, __bf16* __restrict__ KQb,
    __bf16* __restrict__ rh, double* __restrict__ ep)
{
  __shared__ __align__(16) char smem[32768 + 32];
  int blk = blockIdx.x, tid = threadIdx.x;
  v4f acc[4][4];
  acc_zero(acc);
  if (blk < 156) {
    int my = blk / 12, nx = blk - my * 12;
    gemm_core_bf16(smem, g, DIM, wkq, DIM, my * 128, nx * 128, 0, 24, acc, tid);
    epi_store_bf16_ld(acc, KQb, 1536, my * 128, nx * 128, tid);
  } else {
    int j = blk - 156;
    int ry = j / 24, nx = j - ry * 24;
    gemm_core_bf16(smem, g, DIM, xi_bf, DIM, ry * 128, nx * 128, 0, 24, acc, tid);
    epi_relu_energy(acc, rh, MXI, ry * 128, nx * 128, tid,
                    (double*)(smem + 32768), ep + EP_HOPB + ry * 24 + nx);
  }
}

// ==================================================================
// Dispatch 3: base attention core (P + PT store + energy). grid 192
// (q-split), 512 thr: blk<96 -> half0 (mt 0..6), else half1 (mt 7..12).
// PT written directly (transposed scatter; L2 write-combines) — replaces
// the former ptrans_k dispatch. PT cols 208..223 zero-filled here.
// ==================================================================
__global__ __launch_bounds__(512) void battn_k(
    const __bf16* __restrict__ KQb, __bf16* __restrict__ P,
    __bf16* __restrict__ PT, double* __restrict__ ep)
{
  __shared__ __align__(16) char smem[SM_ATTN];
  int blk = blockIdx.x, tid = threadIdx.x;
  int half = blk >= 96 ? 1 : 0;
  int bh = blk - half * 96;
  int b = bh / HN, h = bh - b * HN;
  dev_stage_kq<512>(smem, KQb + (size_t)(b * SEQ) * 1536 + h * YD, tid);
  __bf16* PTb = PT + (size_t)bh * PAREA;
  // zero PT padding cols [208,224): half0 -> 208..215, half1 -> 216..223
  {
    int c0 = 208 + half * 8;
    for (int i = tid; i < PROWS; i += 512)
      *(v8bf*)(PTb + (size_t)i * PCOLS + c0) = zero8();
  }
  double* slot = half ? (ep + EP_A2B + bh) : (ep + bh);
  dev_attn_core<1, 8>(smem, P, PTb, (size_t)bh * PAREA, slot,
                      half ? 7 : 0, half ? 13 : 7, tid);
}

// ==================================================================
// Dispatch 4: bwdA = attn_bwd z0 (96) | z1 (96) | rh@xiT quarters (312).
// grid 504.
// ==================================================================
__global__ __launch_bounds__(256, 4) void bwdA_k(
    const __bf16* __restrict__ KQb,
    const __bf16* __restrict__ P, const __bf16* __restrict__ PT,
    __bf16* __restrict__ dQg, __bf16* __restrict__ dKg,
    const __bf16* __restrict__ rh, const __bf16* __restrict__ xiT,
    float* __restrict__ dGp)
{
  __shared__ __align__(16) char smem[32768];
  int blk = blockIdx.x, tid = threadIdx.x;
  if (blk < 192) {
    int z = blk / 96, bh = blk - z * 96;
    dev_attn_bwd(smem, KQb, P, PT, dQg, dKg, bh, z, tid);
  } else {
    int j = blk - 192;          // 0..311
    int qd = j / 78, jj = j - qd * 78;
    int my = jj / 6, nx = jj - my * 6;
    v4f acc[4][4];
    acc_zero(acc);
    gemm_core_bf16(smem, rh, MXI, xiT, MXI, my * 128, nx * 128, qd * 768, 24, acc, tid);
    epi_store_f32(acc, dGp + (size_t)qd * NPE, my * 128, nx * 128, tid);
  }
}

// ==================================================================
// Dispatch 5: bwdB = dQg@wqT halves | dKg@wkT halves. grid 312.
// ==================================================================
__global__ __launch_bounds__(256, 4) void bwdB_k(
    const __bf16* __restrict__ dQg, const __bf16* __restrict__ wqT,
    const __bf16* __restrict__ dKg, const __bf16* __restrict__ wkT,
    float* __restrict__ dGp)
{
  __shared__ __align__(16) char smem[32768];
  int blk = blockIdx.x, tid = threadIdx.x;
  int z = blk / 156, jj = blk - z * 156;
  int half = jj / 78, j2 = jj - half * 78;
  int my = j2 / 6, nx = j2 - my * 6;
  const __bf16* A = z ? dKg : dQg;
  const __bf16* B = z ? wkT : wqT;
  v4f acc[4][4];
  acc_zero(acc);
  gemm_core_bf16(smem, A, DIM, B, DIM, my * 128, nx * 128, half * 384, 12, acc, tid);
  epi_store_f32(acc, dGp + (size_t)(4 + z * 2 + half) * NPE, my * 128, nx * 128, tid);
}

// ==================================================================
// Dispatch 6: fused LN-backward (sum 8 partials) + trial axpy+LN. grid 1568.
// ==================================================================
__global__ __launch_bounds__(256) void lnbwd_axpy_k(
    const float* __restrict__ dGp,
    const float* __restrict__ xhat, const float* __restrict__ rstd,
    const float* __restrict__ gamma, const float* __restrict__ delta,
    const float* __restrict__ x, float* __restrict__ grad,
    __bf16* __restrict__ gt, unsigned char* __restrict__ g8)
{
  __shared__ float s[8];
  int tok = blockIdx.x, tid = threadIdx.x;
  size_t base = (size_t)tok * DIM;
  float ga0 = gamma[tid], ga1 = gamma[tid + 256], ga2 = gamma[tid + 512];
  float de0 = delta[tid], de1 = delta[tid + 256], de2 = delta[tid + 512];
  float g0 = 0.f, g1 = 0.f, g2 = 0.f;
#pragma unroll
  for (int pi = 0; pi < 8; pi++) {
    const float* p = dGp + (size_t)pi * NPE;
    g0 += p[base + tid];
    g1 += p[base + tid + 256];
    g2 += p[base + tid + 512];
  }
  float dh0 = g0 * ga0, dh1 = g1 * ga1, dh2 = g2 * ga2;
  float xh0 = xhat[base + tid], xh1 = xhat[base + tid + 256], xh2 = xhat[base + tid + 512];
  float s1 = dh0 + dh1 + dh2;
  float s2 = dh0 * xh0 + dh1 * xh1 + dh2 * xh2;
  for (int o = 32; o; o >>= 1) { s1 += __shfl_xor(s1, o, 64); s2 += __shfl_xor(s2, o, 64); }
  if ((tid & 63) == 0) { s[tid >> 6] = s1; s[4 + (tid >> 6)] = s2; }
  __syncthreads();
  float m1 = (s[0] + s[1] + s[2] + s[3]) * (1.0f / DIM);
  float m2 = (s[4] + s[5] + s[6] + s[7]) * (1.0f / DIM);
  float r = rstd[tok];
  float gr0 = r * (dh0 - m1 - xh0 * m2);
  float gr1 = r * (dh1 - m1 - xh1 * m2);
  float gr2 = r * (dh2 - m1 - xh2 * m2);
  grad[base + tid] = gr0; grad[base + tid + 256] = gr1; grad[base + tid + 512] = gr2;
  float xv0 = x[base + tid], xv1 = x[base + tid + 256], xv2 = x[base + tid + 512];
#pragma unroll
  for (int t = 0; t < 4; t++) {
    float lr = 1.0f / (float)(1 << t);
    float v0 = xv0 - lr * gr0, v1 = xv1 - lr * gr1, v2 = xv2 - lr * gr2;
    float sum = v0 + v1 + v2;
    for (int o = 32; o; o >>= 1) sum += __shfl_xor(sum, o, 64);
    __syncthreads();
    if ((tid & 63) == 0) s[tid >> 6] = sum;
    __syncthreads();
    float mu = (s[0] + s[1] + s[2] + s[3]) * (1.0f / DIM);
    float d0 = v0 - mu, d1 = v1 - mu, d2 = v2 - mu;
    float sq = d0 * d0 + d1 * d1 + d2 * d2;
    for (int o = 32; o; o >>= 1) sq += __shfl_xor(sq, o, 64);
    __syncthreads();
    if ((tid & 63) == 0) s[tid >> 6] = sq;
    __syncthreads();
    float var = (s[0] + s[1] + s[2] + s[3]) * (1.0f / DIM);
    float r2 = rsqrtf(var + LN_EPS_F);
    float o0 = ga0 * (d0 * r2) + de0;
    float o1 = ga1 * (d1 * r2) + de1;
    float o2 = ga2 * (d2 * r2) + de2;
    size_t ob = ((size_t)t * MPAD + tok) * DIM;
    gt[ob + tid] = (__bf16)o0; gt[ob + tid + 256] = (__bf16)o1; gt[ob + tid + 512] = (__bf16)o2;
    g8[ob + tid]       = (unsigned char)(__builtin_amdgcn_cvt_pk_fp8_f32(o0, o0, 0, false) & 0xff);
    g8[ob + tid + 256] = (unsigned char)(__builtin_amdgcn_cvt_pk_fp8_f32(o1, o1, 0, false) & 0xff);
    g8[ob + tid + 512] = (unsigned char)(__builtin_amdgcn_cvt_pk_fp8_f32(o2, o2, 0, false) & 0xff);
  }
}

// ==================================================================
// Dispatch 7: trial K/Q batched GEMM: KQt[t] = gt[t] @ [wk;wq]^T.
// M=1664, N=1536, K=768. grid 624 (4 trials x 13 my x 12 nx),
// XCD-chunked swizzle (624 = 8*78). 32KB LDS -> 4 blocks/CU.
// ==================================================================
__global__ __launch_bounds__(256, 4) void tkq_k(
    const __bf16* __restrict__ gt, const __bf16* __restrict__ wkq,
    __bf16* __restrict__ KQt)
{
  __shared__ __align__(16) char smem[32768];
  int tid = threadIdx.x;
  int blk = blockIdx.x;
  int swz = (blk & 7) * 78 + (blk >> 3);
  int t = swz / 156, j = swz - t * 156;
  int my = j / 12, nx = j - my * 12;
  v4f acc[4][4];
  acc_zero(acc);
  gemm_core_bf16(smem, gt + (size_t)t * MPAD * DIM, DIM, wkq, DIM,
                 my * 128, nx * 128, 0, 24, acc, tid);
  epi_store_bf16_ld(acc, KQt + (size_t)t * MPAD * 1536, 1536,
                    my * 128, nx * 128, tid);
}

// ==================================================================
// Dispatch 8: merged trial attn core + MX fp8 hopfield. grid 1280:
//   blk in [0,768):  tattn on KQt (q-split, XCD-swizzled, 4 waves)
//   blk in [768,1280): hop8 grid-stride 1248 jobs (768%8==0 keeps XCD)
// (256,2) register budget — mx8 needs 120 VGPR + 64 AGPR (no spill).
// ==================================================================
__global__ __launch_bounds__(256, 2) void hoptattn_k(
    const __bf16* __restrict__ KQt,
    const unsigned char* __restrict__ g8, const unsigned char* __restrict__ xi8,
    double* __restrict__ ep)
{
  __shared__ __align__(16) char smem[65568];
  int blk = blockIdx.x, tid = threadIdx.x;
  if (blk < 768) {
    int xcd = blk & 7, q = blk >> 3;        // q: 0..95
    int bt = xcd * 4 + (q & 3);             // 0..31
    int rest = q >> 2;                      // 0..23
    int h = rest >> 1, half = rest & 1;
    int b = bt >> 2, t = bt & 3;
    int bh = b * HN + h;
    const __bf16* Ksrc = KQt + (size_t)t * MPAD * 1536 + (size_t)(b * SEQ) * 1536 + h * YD;
    dev_stage_kq<256>(smem, Ksrc, tid);
    double* slot = half ? (ep + EP_A2T + t * 96 + bh) : (ep + (t + 1) * 96 + bh);
    dev_attn_core<0, 4>(smem, (__bf16*)nullptr, (__bf16*)nullptr, 0, slot,
                        half ? 7 : 0, half ? 13 : 7, tid);
  } else {
    int base = blk - 768;                   // 0..511; (base&7)==(blk&7)
    for (int id = base; id < 1248; id += 512) {
      __syncthreads();
      int xcd = id & 7, q = id >> 3;        // q: 0..155
      int nx = xcd * 3 + q % 3;             // 0..23
      int my = q / 3;                       // 0..51
      dev_gemm_mx8(smem, g8, xi8, ep, my, nx, tid);
    }
  }
}

// ==================================================================
// Dispatch 9: fused reduce+choose+update. grid 624 (grid-stride).
// ==================================================================
__global__ __launch_bounds__(256) void update_k(
    const float* __restrict__ x, const float* __restrict__ grad,
    const double* __restrict__ ep, float* __restrict__ out, int n4)
{
  __shared__ double sm[4];
  __shared__ float chs;
  int tid = threadIdx.x;
  double e[5];
  for (int s = 0; s < 5; s++) {
    double acc = 0.0;
    int a0 = 96 * s;
    int a2 = (s == 0) ? EP_A2B : EP_A2T + 96 * (s - 1);
    for (int i = tid; i < 96; i += 256) acc += ep[a0 + i] + ep[a2 + i];
    int b0 = (s == 0) ? EP_HOPB : EP_HOPT + 312 * (s - 1);
    for (int i = tid; i < 312; i += 256) acc += ep[b0 + i];
    for (int o = 32; o; o >>= 1) acc += __shfl_xor(acc, o, 64);
    if ((tid & 63) == 0) sm[tid >> 6] = acc;
    __syncthreads();
    e[s] = (sm[0] + sm[1]) + (sm[2] + sm[3]);
    __syncthreads();
  }
  if (tid == 0) {
    double e0 = e[0];
    float c = 0.0625f;
    if (e[4] < e0) c = 0.125f;
    if (e[3] < e0) c = 0.25f;
    if (e[2] < e0) c = 0.5f;
    if (e[1] < e0) c = 1.0f;
    chs = c;
  }
  __syncthreads();
  float lr = chs;
  for (int i = blockIdx.x * 256 + tid; i < n4; i += gridDim.x * 256) {
    const float4 xv = ((const float4*)x)[i];
    const float4 gv = ((const float4*)grad)[i];
    float4 o;
    o.x = xv.x - lr * gv.x; o.y = xv.y - lr * gv.y;
    o.z = xv.z - lr * gv.z; o.w = xv.w - lr * gv.w;
    ((float4*)out)[i] = o;
  }
}

// ------------------------------------------------------------------
extern "C" void kernel_launch(void* const* d_in, const int* in_sizes, int n_in,
                              void* d_out, int out_size, void* d_ws, size_t ws_size,
                              hipStream_t stream)
{
  const float* x     = (const float*)d_in[0];
  const float* gamma = (const float*)d_in[1];
  const float* delta = (const float*)d_in[2];
  const float* wk    = (const float*)d_in[3];
  const float* wq    = (const float*)d_in[4];
  const float* xi    = (const float*)d_in[5];
  float* out = (float*)d_out;

  const size_t NE = (size_t)TOK * DIM;
  const size_t NP = NPE;

  double* eparts = (double*)d_ws;                // EP_TOTAL doubles
  float* fp = (float*)(eparts + EP_TOTAL + 8);
  float* xhat = fp;  fp += NE;
  float* grad = fp;  fp += NE;
  float* rstd = fp;  fp += TOK;
  fp += 16;
  float* dGp = (float*)(((uintptr_t)fp + 15) & ~(uintptr_t)15);   // 8 * NP floats
  __bf16* bp = (__bf16*)(dGp + 8 * NP);
  __bf16* g_bf   = bp;  bp += NP;
  __bf16* g_tr   = bp;  bp += 4 * NP;
  __bf16* KQb    = bp;  bp += 2 * NP;   // base K|Q [MPAD][1536]
  __bf16* dQg_bf = bp;  bp += NP;
  __bf16* dKg_bf = bp;  bp += NP;
  __bf16* rh_bf  = bp;  bp += (size_t)MPAD * MXI;
  __bf16* wk_bf  = bp;  bp += (size_t)DIM * DIM;
  __bf16* wq_bf  = bp;  bp += (size_t)DIM * DIM;
  __bf16* wkT_bf = bp;  bp += (size_t)DIM * DIM;
  __bf16* wqT_bf = bp;  bp += (size_t)DIM * DIM;
  __bf16* xi_bf  = bp;  bp += (size_t)MXI * DIM;
  __bf16* xiT_bf = bp;  bp += (size_t)DIM * MXI;
  __bf16* P_bf   = bp;  bp += (size_t)96 * PAREA;
  __bf16* PT_bf  = bp;  bp += (size_t)96 * PAREA;
  unsigned char* g8  = (unsigned char*)bp;  bp += 2 * NP;              // 4*NP bytes
  unsigned char* xi8 = (unsigned char*)bp;  bp += (size_t)MXI * DIM / 2;

  // trial K/Q buffer [4][MPAD][1536] bf16 = 20.4 MB, aliased onto dGp
  // (dGp is dead after lnbwd_axpy_k; 8*NP floats = 40.9 MB >= 20.4 MB)
  __bf16* KQt = (__bf16*)dGp;

  const int n4 = (int)(NE / 4);
  dim3 blk(256);

  // 1. prep
  hipLaunchKernelGGL(prep_k, dim3(8768), blk, 0, stream,
                     x, gamma, delta, wk, wq, xi,
                     g_bf, xhat, rstd, wk_bf, wq_bf, xi_bf, (int*)xi8,
                     wkT_bf, wqT_bf, xiT_bf, g_tr, g8, dQg_bf, dKg_bf);
  // 2. fwd GEMMs: base KQ build + hop base (wk_bf/wq_bf contiguous -> N=1536)
  hipLaunchKernelGGL(fwd_k, dim3(468), blk, 0, stream,
                     g_bf, wk_bf, xi_bf, KQb, rh_bf, eparts);
  // 3. base attn core (P + PT + energy), q-split — ptrans fused away
  hipLaunchKernelGGL(battn_k, dim3(192), dim3(512), 0, stream,
                     KQb, P_bf, PT_bf, eparts);
  // 4. attn_bwd + rh@xiT quarters
  hipLaunchKernelGGL(bwdA_k, dim3(504), blk, 0, stream,
                     KQb, P_bf, PT_bf, dQg_bf, dKg_bf, rh_bf, xiT_bf, dGp);
  // 5. dQg@wqT + dKg@wkT (K-halved)
  hipLaunchKernelGGL(bwdB_k, dim3(312), blk, 0, stream,
                     dQg_bf, wqT_bf, dKg_bf, wkT_bf, dGp);
  // 6. ln_bwd + trial axpy/LN fused
  hipLaunchKernelGGL(lnbwd_axpy_k, dim3(TOK), blk, 0, stream,
                     dGp, xhat, rstd, gamma, delta, x, grad, g_tr, g8);
  // 7. trial K/Q batched GEMM (4 blocks/CU)
  hipLaunchKernelGGL(tkq_k, dim3(624), blk, 0, stream, g_tr, wk_bf, KQt);
  // 8. merged trial attn core + MX fp8 hopfield (overlapped, (256,2))
  hipLaunchKernelGGL(hoptattn_k, dim3(1280), blk, 0, stream,
                     KQt, g8, xi8, eparts);
  // 9. reduce + choose + update
  hipLaunchKernelGGL(update_k, dim3(624), blk, 0, stream,
                     x, grad, eparts, out, n4);
}